// Round 2
// baseline (701.932 us; speedup 1.0000x reference)
//
#include <hip/hip_runtime.h>

#define NB 16
#define NL 4096
#define NH 16
#define ND 64
#define NS 4096
#define NM 256

typedef __fp16 f16;
typedef __attribute__((ext_vector_type(8)))  __fp16 f16x8;
typedef __attribute__((ext_vector_type(4)))  __fp16 f16x4;
typedef __attribute__((ext_vector_type(2)))  __fp16 f16x2;
typedef __attribute__((ext_vector_type(4)))  float  f32x4;
typedef __attribute__((ext_vector_type(16))) float  f32x16;

__device__ __forceinline__ void gload_lds16(const void* g, void* l) {
  __builtin_amdgcn_global_load_lds(
      (const __attribute__((address_space(1))) void*)g,
      (__attribute__((address_space(3))) void*)l, 16, 0, 0);
}

// ---------------- kernel 0: W fp32 -> fp16 ----------------
__global__ __launch_bounds__(256) void k_wcvt(const float* __restrict__ W,
                                              f16* __restrict__ W16) {
  const int i = blockIdx.x * 256 + threadIdx.x;  // 262144 float4s exactly
  f32x4 v = ((const f32x4*)W)[i];
  f16x2 a = __builtin_amdgcn_cvt_pkrtz(v[0], v[1]);
  f16x2 b = __builtin_amdgcn_cvt_pkrtz(v[2], v[3]);
  f16x4 o; o[0] = a[0]; o[1] = a[1]; o[2] = b[0]; o[3] = b[1];
  ((f16x4*)W16)[i] = o;
}

// ---------------- kernel 1: squeeze GEMM ------------------
// block = one (tensor t, batch b, head h): Out[256 m][64 d] = W(256x4096) @ X[b,:,h,:](4096x64)
// 256 threads = 4 waves; wave w owns m-rows [64w, 64w+64); 32x32x16 f16 MFMA; BK=64.
__global__ __launch_bounds__(256, 2) void k_squeeze(
    const f16* __restrict__ W16, const float* __restrict__ keys,
    const float* __restrict__ values, const float* __restrict__ bias,
    f16* __restrict__ Ksq, f16* __restrict__ VsqT) {
  const int h = blockIdx.x & 15;
  const int b = (blockIdx.x >> 4) & 15;
  const int t = blockIdx.x >> 8;
  const float* __restrict__ X = t ? values : keys;

  __shared__ __align__(16) f16 Wt[256 * 64];  // 32 KB, rows 128B, XOR-swizzled content
  __shared__ __align__(16) f16 XT[64 * 72];   // 9 KB, [n][72] padded, transposed X tile

  const int tid  = threadIdx.x;
  const int lane = tid & 63;
  const int w    = tid >> 6;     // wave 0..3
  const int l31  = lane & 31;
  const int g    = lane >> 5;    // 0/1

  // global_load_lds per-lane source for W tile: lane j -> (row 8*ii + j>>3, slot j&7)
  const int  wrsub = lane >> 3;
  const int  wslot = lane & 7;
  const char* Wg = (const char*)W16 + (long)wrsub * (NS * 2) + ((wslot * 16) ^ (wrsub << 4));

  // X staging: thread -> s-pair sp (0..31), n-group ng0 (0..7), units u=0/1 add +8 to ng
  const int sp  = tid & 31;
  const int ng0 = tid >> 5;
  const float* Xb = X + ((long)b * NS) * (NH * ND) + h * ND;

  f32x16 acc[2][2];
#pragma unroll
  for (int mi = 0; mi < 2; ++mi)
#pragma unroll
    for (int di = 0; di < 2; ++di)
#pragma unroll
      for (int q = 0; q < 16; ++q) acc[mi][di][q] = 0.f;

  // prologue: X regs for kt=0
  f32x4 xr[2][2];
#pragma unroll
  for (int u = 0; u < 2; ++u)
#pragma unroll
    for (int r = 0; r < 2; ++r)
      xr[u][r] = *(const f32x4*)(Xb + (long)(2 * sp + r) * (NH * ND) + (ng0 + 8 * u) * 4);

  for (int kt = 0; kt < NS / 64; ++kt) {
    const int k0 = kt * 64;
    __syncthreads();  // LDS free (prev iter's reads done)
    // stage W tile via global_load_lds (wave w stages its own rows [64w,64w+64))
    {
      const char* wg = Wg + (long)k0 * 2;
#pragma unroll
      for (int i = 0; i < 8; ++i) {
        const int ii = w * 8 + i;  // 8-row group
        gload_lds16(wg + (long)ii * 8 * (NS * 2), (char*)Wt + ii * 1024);
      }
    }
    // stage X tile (transposed, fp16)
#pragma unroll
    for (int u = 0; u < 2; ++u) {
      const int ng = ng0 + 8 * u;
#pragma unroll
      for (int c = 0; c < 4; ++c) {
        f16x2 p = __builtin_amdgcn_cvt_pkrtz(xr[u][0][c], xr[u][1][c]);
        *(f16x2*)((char*)XT + (ng * 4 + c) * 144 + sp * 4) = p;
      }
    }
    __syncthreads();
    // prefetch next X tile into regs (overlaps with MFMA below)
    if (kt + 1 < NS / 64) {
#pragma unroll
      for (int u = 0; u < 2; ++u)
#pragma unroll
        for (int r = 0; r < 2; ++r)
          xr[u][r] = *(const f32x4*)(Xb + (long)(k0 + 64 + 2 * sp + r) * (NH * ND) +
                                     (ng0 + 8 * u) * 4);
    }
    // compute: 4 k-steps of 16
#pragma unroll
    for (int ks = 0; ks < 4; ++ks) {
      f16x8 af[2], bf[2];
#pragma unroll
      for (int mi = 0; mi < 2; ++mi) {
        const int row  = w * 64 + mi * 32 + l31;
        const int colb = (ks * 32 + g * 16) ^ ((row & 7) << 4);
        af[mi] = *(const f16x8*)((const char*)Wt + row * 128 + colb);
      }
#pragma unroll
      for (int di = 0; di < 2; ++di) {
        const int n = di * 32 + l31;
        bf[di] = *(const f16x8*)((const char*)XT + n * 144 + ks * 32 + g * 16);
      }
#pragma unroll
      for (int mi = 0; mi < 2; ++mi)
#pragma unroll
        for (int di = 0; di < 2; ++di)
          acc[mi][di] =
              __builtin_amdgcn_mfma_f32_32x32x16_f16(af[mi], bf[di], acc[mi][di], 0, 0, 0);
    }
  }

  // epilogue: + bias[m], write fp16
  const long bh = b * 16 + h;
  if (t == 0) {
    f16* K = Ksq + bh * (NM * ND);  // [m][d]
#pragma unroll
    for (int mi = 0; mi < 2; ++mi)
#pragma unroll
      for (int di = 0; di < 2; ++di)
#pragma unroll
        for (int r = 0; r < 16; ++r) {
          const int m = w * 64 + mi * 32 + (r & 3) + 8 * (r >> 2) + 4 * g;
          const int d = di * 32 + l31;
          K[m * 64 + d] = (f16)(acc[mi][di][r] + bias[m]);
        }
  } else {
    f16* V = VsqT + bh * (ND * NM);  // [d][m]
#pragma unroll
    for (int mi = 0; mi < 2; ++mi)
#pragma unroll
      for (int di = 0; di < 2; ++di)
#pragma unroll
        for (int q = 0; q < 4; ++q) {
          const int m0 = w * 64 + mi * 32 + 8 * q + 4 * g;
          const int d  = di * 32 + l31;
          f16x2 p0 = __builtin_amdgcn_cvt_pkrtz(acc[mi][di][q * 4 + 0] + bias[m0 + 0],
                                                acc[mi][di][q * 4 + 1] + bias[m0 + 1]);
          f16x2 p1 = __builtin_amdgcn_cvt_pkrtz(acc[mi][di][q * 4 + 2] + bias[m0 + 2],
                                                acc[mi][di][q * 4 + 3] + bias[m0 + 3]);
          f16x4 pv; pv[0] = p0[0]; pv[1] = p0[1]; pv[2] = p1[0]; pv[3] = p1[1];
          *(f16x4*)(V + d * 256 + m0) = pv;
        }
  }
}

// ---------------- kernel 2: attention ---------------------
// block = (b,h, 64 q-rows); 4 independent waves (16 q-rows each), barrier-free.
// Swapped QK: S^T = mfma(K_sq, Q) -> lane holds one q-row's scores; softmax in-lane + 2 shfl.
// PV: ctx^T = mfma(V^T, P) with P via wave-private LDS rows.
__global__ __launch_bounds__(256, 2) void k_attn(const float* __restrict__ Q,
                                                 const f16* __restrict__ Ksq,
                                                 const f16* __restrict__ VsqT,
                                                 float* __restrict__ Out) {
  // XCD-aware: each of 8 XCDs owns 32 contiguous (b,h) slices (K/V stay L2-hot)
  const int xcd = blockIdx.x & 7;
  const int loc = blockIdx.x >> 3;          // 0..2047
  const int bh  = xcd * 32 + (loc >> 6);    // 0..255
  const int lt  = loc & 63;
  const int b = bh >> 4, h = bh & 15;
  const int l0 = lt * 64;

  __shared__ __align__(16) f16 Ps[64 * 264];  // [qrow][264] padded, wave-private rows

  const int tid = threadIdx.x, lane = tid & 63, w = tid >> 6;
  const int l15 = lane & 15, g = lane >> 4;  // g 0..3
  const int qrow = w * 16 + l15;

  const f16* Kb = Ksq + (long)bh * (NM * ND);
  const f16* Vb = VsqT + (long)bh * (ND * NM);

  // Q B-frags straight from global (fp32 -> fp16), k-run d = ks*32 + g*8 + j
  const float* qg = Q + (((long)b * NL + l0 + qrow) * NH + h) * ND;
  f16x8 qf[2];
#pragma unroll
  for (int ks = 0; ks < 2; ++ks) {
    f32x4 u0 = *(const f32x4*)(qg + ks * 32 + g * 8);
    f32x4 u1 = *(const f32x4*)(qg + ks * 32 + g * 8 + 4);
    union { f16x8 v; f16x2 h2[4]; } pk;
    pk.h2[0] = __builtin_amdgcn_cvt_pkrtz(u0[0], u0[1]);
    pk.h2[1] = __builtin_amdgcn_cvt_pkrtz(u0[2], u0[3]);
    pk.h2[2] = __builtin_amdgcn_cvt_pkrtz(u1[0], u1[1]);
    pk.h2[3] = __builtin_amdgcn_cvt_pkrtz(u1[2], u1[3]);
    qf[ks] = pk.v;
  }

  // scores: S^T[m][qcol], 16 m-frags
  f32x4 sa[16];
#pragma unroll
  for (int mf = 0; mf < 16; ++mf) {
    const f16* kp = Kb + (mf * 16 + l15) * 64 + g * 8;
    f16x8 a0 = *(const f16x8*)(kp);
    f16x8 a1 = *(const f16x8*)(kp + 32);
    f32x4 z = {0.f, 0.f, 0.f, 0.f};
    z      = __builtin_amdgcn_mfma_f32_16x16x32_f16(a0, qf[0], z, 0, 0, 0);
    sa[mf] = __builtin_amdgcn_mfma_f32_16x16x32_f16(a1, qf[1], z, 0, 0, 0);
  }

  // softmax over m (row = this lane's qrow); scale folded into exp2
  const float c = 0.125f * 1.44269504088896f;
  float mx = -1e30f;
#pragma unroll
  for (int mf = 0; mf < 16; ++mf)
#pragma unroll
    for (int r = 0; r < 4; ++r) mx = fmaxf(mx, sa[mf][r]);
  mx = fmaxf(mx, __shfl_xor(mx, 16));
  mx = fmaxf(mx, __shfl_xor(mx, 32));
  float sum = 0.f;
#pragma unroll
  for (int mf = 0; mf < 16; ++mf)
#pragma unroll
    for (int r = 0; r < 4; ++r) {
      const float p = exp2f((sa[mf][r] - mx) * c);
      sa[mf][r] = p;
      sum += p;
    }
  sum += __shfl_xor(sum, 16);
  sum += __shfl_xor(sum, 32);
  const float inv = 1.0f / sum;

  // write P (lane's values all belong to row qrow; m = mf*16 + g*4 + r)
  char* prow = (char*)Ps + qrow * 528;
#pragma unroll
  for (int mf = 0; mf < 16; ++mf) {
    f16x2 p0 = __builtin_amdgcn_cvt_pkrtz(sa[mf][0] * inv, sa[mf][1] * inv);
    f16x2 p1 = __builtin_amdgcn_cvt_pkrtz(sa[mf][2] * inv, sa[mf][3] * inv);
    f16x4 pv; pv[0] = p0[0]; pv[1] = p0[1]; pv[2] = p1[0]; pv[3] = p1[1];
    *(f16x4*)(prow + mf * 32 + g * 8) = pv;
  }

  // PV: ctx^T[d][qcol] += V^T-frag x P-frag  (wave-private P rows -> no barrier)
  f32x4 o[4];
#pragma unroll
  for (int df = 0; df < 4; ++df)
#pragma unroll
    for (int r = 0; r < 4; ++r) o[df][r] = 0.f;
#pragma unroll
  for (int ks = 0; ks < 8; ++ks) {
    f16x8 pf = *(const f16x8*)((char*)Ps + qrow * 528 + ks * 64 + g * 16);
#pragma unroll
    for (int df = 0; df < 4; ++df) {
      f16x8 vf = *(const f16x8*)(Vb + (df * 16 + l15) * 256 + ks * 32 + g * 8);
      o[df] = __builtin_amdgcn_mfma_f32_16x16x32_f16(vf, pf, o[df], 0, 0, 0);
    }
  }

  // epilogue: lane holds 4 consecutive d per frag at its qrow -> float4 stores
  float* og = Out + (((long)b * NL + l0 + qrow) * NH + h) * ND;
#pragma unroll
  for (int df = 0; df < 4; ++df) *(f32x4*)(og + df * 16 + g * 4) = o[df];
}

extern "C" void kernel_launch(void* const* d_in, const int* in_sizes, int n_in,
                              void* d_out, int out_size, void* d_ws, size_t ws_size,
                              hipStream_t stream) {
  const float* Qp   = (const float*)d_in[0];
  const float* Kp   = (const float*)d_in[1];
  const float* Vp   = (const float*)d_in[2];
  const float* Wp   = (const float*)d_in[3];
  const float* bp   = (const float*)d_in[4];
  float*       Outp = (float*)d_out;

  char* ws = (char*)d_ws;
  f16* W16  = (f16*)ws;                                  // 2 MB
  f16* Ksq  = (f16*)(ws + (2l << 20));                   // 8 MB
  f16* VsqT = (f16*)(ws + (2l << 20) + (8l << 20));      // 8 MB

  hipLaunchKernelGGL(k_wcvt, dim3(1024), dim3(256), 0, stream, Wp, W16);
  hipLaunchKernelGGL(k_squeeze, dim3(512), dim3(256), 0, stream, W16, Kp, Vp, bp, Ksq, VsqT);
  hipLaunchKernelGGL(k_attn, dim3(16384), dim3(256), 0, stream, Qp, Ksq, VsqT, Outp);
}

// Round 3
// 437.493 us; speedup vs baseline: 1.6044x; 1.6044x over previous
//
#include <hip/hip_runtime.h>

#define NB 16
#define NL 4096
#define NH 16
#define ND 64
#define NS 4096
#define NM 256

typedef __fp16 f16;
typedef __attribute__((ext_vector_type(8)))  __fp16 f16x8;
typedef __attribute__((ext_vector_type(4)))  __fp16 f16x4;
typedef __attribute__((ext_vector_type(2)))  __fp16 f16x2;
typedef __attribute__((ext_vector_type(4)))  float  f32x4;
typedef __attribute__((ext_vector_type(16))) float  f32x16;

__device__ __forceinline__ void gload_lds16(const void* g, void* l) {
  __builtin_amdgcn_global_load_lds(
      (const __attribute__((address_space(1))) void*)g,
      (__attribute__((address_space(3))) void*)l, 16, 0, 0);
}

__device__ __forceinline__ int pk2(float a, float b) {
  f16x2 t = __builtin_amdgcn_cvt_pkrtz(a, b);
  union { f16x2 h; int i; } u; u.h = t; return u.i;
}

// ---------------- kernel 0: W fp32 -> fp16 ----------------
__global__ __launch_bounds__(256) void k_wcvt(const float* __restrict__ W,
                                              f16* __restrict__ W16) {
  const int i = blockIdx.x * 256 + threadIdx.x;  // 262144 float4s exactly
  f32x4 v = ((const f32x4*)W)[i];
  f16x2 a = __builtin_amdgcn_cvt_pkrtz(v[0], v[1]);
  f16x2 b = __builtin_amdgcn_cvt_pkrtz(v[2], v[3]);
  f16x4 o; o[0] = a[0]; o[1] = a[1]; o[2] = b[0]; o[3] = b[1];
  ((f16x4*)W16)[i] = o;
}

// ---------------- kernel 1: squeeze GEMM ------------------
// block = one (tensor t, batch b, head h): Out[256 m][64 d] = W(256x4096) @ X[b,:,h,:](4096x64)
// Outputs in k-run-major layouts for k_attn LDS identity staging:
//   Ksq[bh][u=d/8][m][d&7]  (QK A-operand runs)
//   Vsq[bh][u=m/8][d][m&7]  (PV A-operand runs)
__global__ __launch_bounds__(256, 2) void k_squeeze(
    const f16* __restrict__ W16, const float* __restrict__ keys,
    const float* __restrict__ values, const float* __restrict__ bias,
    f16* __restrict__ Ksq, f16* __restrict__ Vsq) {
  const int h = blockIdx.x & 15;
  const int b = (blockIdx.x >> 4) & 15;
  const int t = blockIdx.x >> 8;
  const float* __restrict__ X = t ? values : keys;

  __shared__ __align__(16) f16 Wt[256 * 64];  // 32 KB, rows 128B, XOR-swizzled content
  __shared__ __align__(16) f16 XT[64 * 72];   // 9 KB, [n][72] padded, transposed X tile

  const int tid  = threadIdx.x;
  const int lane = tid & 63;
  const int w    = tid >> 6;     // wave 0..3
  const int l31  = lane & 31;
  const int g    = lane >> 5;    // 0/1

  const int  wrsub = lane >> 3;
  const int  wslot = lane & 7;
  const char* Wg = (const char*)W16 + (long)wrsub * (NS * 2) + ((wslot * 16) ^ (wrsub << 4));

  const int sp  = tid & 31;
  const int ng0 = tid >> 5;
  const float* Xb = X + ((long)b * NS) * (NH * ND) + h * ND;

  f32x16 acc[2][2];
#pragma unroll
  for (int mi = 0; mi < 2; ++mi)
#pragma unroll
    for (int di = 0; di < 2; ++di)
#pragma unroll
      for (int q = 0; q < 16; ++q) acc[mi][di][q] = 0.f;

  f32x4 xr[2][2];
#pragma unroll
  for (int u = 0; u < 2; ++u)
#pragma unroll
    for (int r = 0; r < 2; ++r)
      xr[u][r] = *(const f32x4*)(Xb + (long)(2 * sp + r) * (NH * ND) + (ng0 + 8 * u) * 4);

  for (int kt = 0; kt < NS / 64; ++kt) {
    const int k0 = kt * 64;
    __syncthreads();
    {
      const char* wg = Wg + (long)k0 * 2;
#pragma unroll
      for (int i = 0; i < 8; ++i) {
        const int ii = w * 8 + i;
        gload_lds16(wg + (long)ii * 8 * (NS * 2), (char*)Wt + ii * 1024);
      }
    }
#pragma unroll
    for (int u = 0; u < 2; ++u) {
      const int ng = ng0 + 8 * u;
#pragma unroll
      for (int c = 0; c < 4; ++c) {
        f16x2 p = __builtin_amdgcn_cvt_pkrtz(xr[u][0][c], xr[u][1][c]);
        *(f16x2*)((char*)XT + (ng * 4 + c) * 144 + sp * 4) = p;
      }
    }
    __syncthreads();
    if (kt + 1 < NS / 64) {
#pragma unroll
      for (int u = 0; u < 2; ++u)
#pragma unroll
        for (int r = 0; r < 2; ++r)
          xr[u][r] = *(const f32x4*)(Xb + (long)(k0 + 64 + 2 * sp + r) * (NH * ND) +
                                     (ng0 + 8 * u) * 4);
    }
#pragma unroll
    for (int ks = 0; ks < 4; ++ks) {
      f16x8 af[2], bf[2];
#pragma unroll
      for (int mi = 0; mi < 2; ++mi) {
        const int row  = w * 64 + mi * 32 + l31;
        const int colb = (ks * 32 + g * 16) ^ ((row & 7) << 4);
        af[mi] = *(const f16x8*)((const char*)Wt + row * 128 + colb);
      }
#pragma unroll
      for (int di = 0; di < 2; ++di) {
        const int n = di * 32 + l31;
        bf[di] = *(const f16x8*)((const char*)XT + n * 144 + ks * 32 + g * 16);
      }
#pragma unroll
      for (int mi = 0; mi < 2; ++mi)
#pragma unroll
        for (int di = 0; di < 2; ++di)
          acc[mi][di] =
              __builtin_amdgcn_mfma_f32_32x32x16_f16(af[mi], bf[di], acc[mi][di], 0, 0, 0);
    }
  }

  const long bh = b * 16 + h;
  if (t == 0) {
    f16* K = Ksq + bh * (NM * ND);  // [u=d/8][m][d&7]
#pragma unroll
    for (int mi = 0; mi < 2; ++mi)
#pragma unroll
      for (int di = 0; di < 2; ++di)
#pragma unroll
        for (int r = 0; r < 16; ++r) {
          const int m = w * 64 + mi * 32 + (r & 3) + 8 * (r >> 2) + 4 * g;
          const int d = di * 32 + l31;
          K[((d >> 3) * 256 + m) * 8 + (d & 7)] = (f16)(acc[mi][di][r] + bias[m]);
        }
  } else {
    f16* V = Vsq + bh * (ND * NM);  // [u=m/8][d][m&7]
#pragma unroll
    for (int mi = 0; mi < 2; ++mi)
#pragma unroll
      for (int di = 0; di < 2; ++di)
#pragma unroll
        for (int q = 0; q < 4; ++q) {
          const int m0 = w * 64 + mi * 32 + 8 * q + 4 * g;  // m0&7 == 4g
          const int d  = di * 32 + l31;
          f16x2 p0 = __builtin_amdgcn_cvt_pkrtz(acc[mi][di][q * 4 + 0] + bias[m0 + 0],
                                                acc[mi][di][q * 4 + 1] + bias[m0 + 1]);
          f16x2 p1 = __builtin_amdgcn_cvt_pkrtz(acc[mi][di][q * 4 + 2] + bias[m0 + 2],
                                                acc[mi][di][q * 4 + 3] + bias[m0 + 3]);
          f16x4 pv; pv[0] = p0[0]; pv[1] = p0[1]; pv[2] = p1[0]; pv[3] = p1[1];
          *(f16x4*)(V + ((m0 >> 3) * 64 + d) * 8 + 4 * g) = pv;
        }
  }
}

// ---------------- kernel 2: attention (persistent K/V-in-LDS) ----------------
// 512 blocks (2 per (b,h)); block stages K,V once (64 KB LDS, k-run-major,
// conflict-free b128 reads), then loops 16 q-tiles of 128 rows (32 rows/wave).
// QK: S^T = mfma32x32x16(K, Q); softmax in-lane (lane owns one q-col) + shfl_xor(32).
// P->PV B-operand fully in-register: cvt_pkrtz + v_permlane32_swap_b32.
__global__ __launch_bounds__(256, 2) void k_attn(const float* __restrict__ Q,
                                                 const f16* __restrict__ Ksq,
                                                 const f16* __restrict__ Vsq,
                                                 float* __restrict__ Out) {
  const int xcd   = blockIdx.x & 7;
  const int local = blockIdx.x >> 3;        // 0..63
  const int bh    = xcd * 32 + (local >> 1);
  const int chunk = local & 1;
  const int b = bh >> 4, h = bh & 15;

  __shared__ __align__(16) f16 Klds[8 * 256 * 8];   // [u=d/8][m][8]  32 KB
  __shared__ __align__(16) f16 Vlds[32 * 64 * 8];   // [u=m/8][d][8]  32 KB

  const int tid = threadIdx.x, lane = tid & 63, w = tid >> 6;
  const int q = lane & 31, hi = lane >> 5;

  // stage K/V (identity copy, global_load_lds 16B)
  {
    const f16* Kg = Ksq + (long)bh * 16384;
    const f16* Vg = Vsq + (long)bh * 16384;
#pragma unroll
    for (int i = 0; i < 8; ++i)
      gload_lds16(Kg + w * 4096 + i * 512 + lane * 8, (char*)Klds + w * 8192 + i * 1024);
#pragma unroll
    for (int i = 0; i < 8; ++i)
      gload_lds16(Vg + w * 4096 + i * 512 + lane * 8, (char*)Vlds + w * 8192 + i * 1024);
  }
  __syncthreads();

  const float* Qlane = Q   + (((long)b * NL + q) * NH + h) * ND;
  float*       Olane = Out + (((long)b * NL + q) * NH + h) * ND;
  const float  c = 0.125f * 1.44269504088896f;

  for (int it = 0; it < 16; ++it) {
    const int row0 = chunk * 2048 + it * 128 + w * 32;  // + q per lane
    const float* qp = Qlane + (long)row0 * (NH * ND) + hi * 8;

    // issue all Q loads for this tile
    f32x4 qv[8];
#pragma unroll
    for (int kt = 0; kt < 4; ++kt) {
      qv[2 * kt]     = *(const f32x4*)(qp + kt * 16);
      qv[2 * kt + 1] = *(const f32x4*)(qp + kt * 16 + 4);
    }

    // QK^T: sa[mf] = S^T[m-frag][qcol]
    f32x16 sa[8];
#pragma unroll
    for (int mf = 0; mf < 8; ++mf)
#pragma unroll
      for (int r = 0; r < 16; ++r) sa[mf][r] = 0.f;

#pragma unroll
    for (int kt = 0; kt < 4; ++kt) {
      union { f16x8 v; f16x2 h2[4]; } qb;
      qb.h2[0] = __builtin_amdgcn_cvt_pkrtz(qv[2 * kt][0], qv[2 * kt][1]);
      qb.h2[1] = __builtin_amdgcn_cvt_pkrtz(qv[2 * kt][2], qv[2 * kt][3]);
      qb.h2[2] = __builtin_amdgcn_cvt_pkrtz(qv[2 * kt + 1][0], qv[2 * kt + 1][1]);
      qb.h2[3] = __builtin_amdgcn_cvt_pkrtz(qv[2 * kt + 1][2], qv[2 * kt + 1][3]);
#pragma unroll
      for (int mf = 0; mf < 8; ++mf) {
        f16x8 ka = *(const f16x8*)((const char*)Klds +
                                   ((2 * kt + hi) * 256 + mf * 32 + q) * 16);
        sa[mf] = __builtin_amdgcn_mfma_f32_32x32x16_f16(ka, qb.v, sa[mf], 0, 0, 0);
      }
    }

    // softmax along m (this lane holds 128 of 256 values of its q-col; partner lane^32 rest)
    float mx = -1e30f;
#pragma unroll
    for (int mf = 0; mf < 8; ++mf)
#pragma unroll
      for (int r = 0; r < 16; ++r) mx = fmaxf(mx, sa[mf][r]);
    mx = fmaxf(mx, __shfl_xor(mx, 32));
    float sum = 0.f;
#pragma unroll
    for (int mf = 0; mf < 8; ++mf)
#pragma unroll
      for (int r = 0; r < 16; ++r) {
        const float p = exp2f((sa[mf][r] - mx) * c);
        sa[mf][r] = p;
        sum += p;
      }
    sum += __shfl_xor(sum, 32);
    const float inv = 1.0f / sum;

    // PV: o[df] = ctx^T[d-frag][qcol]; P B-frags via cvt_pk + permlane32_swap
    f32x16 o[2];
#pragma unroll
    for (int df = 0; df < 2; ++df)
#pragma unroll
      for (int r = 0; r < 16; ++r) o[df][r] = 0.f;

#pragma unroll
    for (int t = 0; t < 16; ++t) {
      const int fp = t >> 1, s = t & 1;
      int a0 = pk2(sa[fp][8 * s + 0] * inv, sa[fp][8 * s + 1] * inv);
      int a1 = pk2(sa[fp][8 * s + 2] * inv, sa[fp][8 * s + 3] * inv);
      int b0 = pk2(sa[fp][8 * s + 4] * inv, sa[fp][8 * s + 5] * inv);
      int b1 = pk2(sa[fp][8 * s + 6] * inv, sa[fp][8 * s + 7] * inv);
      asm volatile("v_permlane32_swap_b32 %0, %1" : "+v"(a0), "+v"(b0));
      asm volatile("v_permlane32_swap_b32 %0, %1" : "+v"(a1), "+v"(b1));
      union { int w4[4]; f16x8 v; } pb;
      pb.w4[0] = a0; pb.w4[1] = a1; pb.w4[2] = b0; pb.w4[3] = b1;
#pragma unroll
      for (int df = 0; df < 2; ++df) {
        f16x8 va = *(const f16x8*)((const char*)Vlds +
                                   ((2 * t + hi) * 64 + df * 32 + q) * 16);
        o[df] = __builtin_amdgcn_mfma_f32_32x32x16_f16(va, pb.v, o[df], 0, 0, 0);
      }
    }

    // store: lane q-col = row (row0+q); d = df*32 + rq*8 + hi*4 + (0..3)
    float* op = Olane + (long)row0 * (NH * ND);
#pragma unroll
    for (int df = 0; df < 2; ++df)
#pragma unroll
      for (int rq = 0; rq < 4; ++rq) {
        f32x4 st;
        st[0] = o[df][rq * 4 + 0]; st[1] = o[df][rq * 4 + 1];
        st[2] = o[df][rq * 4 + 2]; st[3] = o[df][rq * 4 + 3];
        *(f32x4*)(op + df * 32 + rq * 8 + hi * 4) = st;
      }
  }
}

extern "C" void kernel_launch(void* const* d_in, const int* in_sizes, int n_in,
                              void* d_out, int out_size, void* d_ws, size_t ws_size,
                              hipStream_t stream) {
  const float* Qp   = (const float*)d_in[0];
  const float* Kp   = (const float*)d_in[1];
  const float* Vp   = (const float*)d_in[2];
  const float* Wp   = (const float*)d_in[3];
  const float* bp   = (const float*)d_in[4];
  float*       Outp = (float*)d_out;

  char* ws = (char*)d_ws;
  f16* W16 = (f16*)ws;                              // 2 MB
  f16* Ksq = (f16*)(ws + (2l << 20));               // 8 MB
  f16* Vsq = (f16*)(ws + (2l << 20) + (8l << 20));  // 8 MB

  hipLaunchKernelGGL(k_wcvt, dim3(1024), dim3(256), 0, stream, Wp, W16);
  hipLaunchKernelGGL(k_squeeze, dim3(512), dim3(256), 0, stream, W16, Kp, Vp, bp, Ksq, Vsq);
  hipLaunchKernelGGL(k_attn, dim3(512), dim3(256), 0, stream, Qp, Ksq, Vsq, Outp);
}

// Round 5
// 314.979 us; speedup vs baseline: 2.2285x; 1.3890x over previous
//
#include <hip/hip_runtime.h>

#define NB 16
#define NL 4096
#define NH 16
#define ND 64
#define NS 4096
#define NM 256

typedef __fp16 f16;
typedef __attribute__((ext_vector_type(8)))  __fp16 f16x8;
typedef __attribute__((ext_vector_type(4)))  __fp16 f16x4;
typedef __attribute__((ext_vector_type(2)))  __fp16 f16x2;
typedef __attribute__((ext_vector_type(4)))  float  f32x4;
typedef __attribute__((ext_vector_type(16))) float  f32x16;

__device__ __forceinline__ void gload_lds16(const void* g, void* l) {
  __builtin_amdgcn_global_load_lds(
      (const __attribute__((address_space(1))) void*)g,
      (__attribute__((address_space(3))) void*)l, 16, 0, 0);
}

__device__ __forceinline__ int pk2(float a, float b) {
  f16x2 t = __builtin_amdgcn_cvt_pkrtz(a, b);
  union { f16x2 h; int i; } u; u.h = t; return u.i;
}

// ---------------- kernel 0: W fp32 -> fp16 ----------------
__global__ __launch_bounds__(256) void k_wcvt(const float* __restrict__ W,
                                              f16* __restrict__ W16) {
  const int i = blockIdx.x * 256 + threadIdx.x;  // 262144 float4s exactly
  f32x4 v = ((const f32x4*)W)[i];
  f16x2 a = __builtin_amdgcn_cvt_pkrtz(v[0], v[1]);
  f16x2 b = __builtin_amdgcn_cvt_pkrtz(v[2], v[3]);
  f16x4 o; o[0] = a[0]; o[1] = a[1]; o[2] = b[0]; o[3] = b[1];
  ((f16x4*)W16)[i] = o;
}

// ---------------- kernel 1: squeeze GEMM ------------------
// block = one (tensor t, batch b, head h): Out[256 m][64 d] = W(256x4096) @ X[b,:,h,:](4096x64)
// Outputs in k-run-major layouts for k_attn LDS identity staging:
//   Ksq[bh][u=d/8][m][d&7]  (QK A-operand runs)
//   Vsq[bh][u=m/8][d][m&7]  (PV A-operand runs)
__global__ __launch_bounds__(256, 2) void k_squeeze(
    const f16* __restrict__ W16, const float* __restrict__ keys,
    const float* __restrict__ values, const float* __restrict__ bias,
    f16* __restrict__ Ksq, f16* __restrict__ Vsq) {
  const int h = blockIdx.x & 15;
  const int b = (blockIdx.x >> 4) & 15;
  const int t = blockIdx.x >> 8;
  const float* __restrict__ X = t ? values : keys;

  __shared__ __align__(16) f16 Wt[256 * 64];  // 32 KB, rows 128B, XOR-swizzled content
  __shared__ __align__(16) f16 XT[64 * 72];   // 9 KB, [n][72] padded, transposed X tile

  const int tid  = threadIdx.x;
  const int lane = tid & 63;
  const int w    = tid >> 6;     // wave 0..3
  const int l31  = lane & 31;
  const int g    = lane >> 5;    // 0/1

  const int  wrsub = lane >> 3;
  const int  wslot = lane & 7;
  const char* Wg = (const char*)W16 + (long)wrsub * (NS * 2) + ((wslot * 16) ^ (wrsub << 4));

  const int sp  = tid & 31;
  const int ng0 = tid >> 5;
  const float* Xb = X + ((long)b * NS) * (NH * ND) + h * ND;

  f32x16 acc[2][2];
#pragma unroll
  for (int mi = 0; mi < 2; ++mi)
#pragma unroll
    for (int di = 0; di < 2; ++di)
#pragma unroll
      for (int q = 0; q < 16; ++q) acc[mi][di][q] = 0.f;

  f32x4 xr[2][2];
#pragma unroll
  for (int u = 0; u < 2; ++u)
#pragma unroll
    for (int r = 0; r < 2; ++r)
      xr[u][r] = *(const f32x4*)(Xb + (long)(2 * sp + r) * (NH * ND) + (ng0 + 8 * u) * 4);

  for (int kt = 0; kt < NS / 64; ++kt) {
    const int k0 = kt * 64;
    __syncthreads();
    {
      const char* wg = Wg + (long)k0 * 2;
#pragma unroll
      for (int i = 0; i < 8; ++i) {
        const int ii = w * 8 + i;
        gload_lds16(wg + (long)ii * 8 * (NS * 2), (char*)Wt + ii * 1024);
      }
    }
#pragma unroll
    for (int u = 0; u < 2; ++u) {
      const int ng = ng0 + 8 * u;
#pragma unroll
      for (int c = 0; c < 4; ++c) {
        f16x2 p = __builtin_amdgcn_cvt_pkrtz(xr[u][0][c], xr[u][1][c]);
        *(f16x2*)((char*)XT + (ng * 4 + c) * 144 + sp * 4) = p;
      }
    }
    __syncthreads();
    if (kt + 1 < NS / 64) {
#pragma unroll
      for (int u = 0; u < 2; ++u)
#pragma unroll
        for (int r = 0; r < 2; ++r)
          xr[u][r] = *(const f32x4*)(Xb + (long)(k0 + 64 + 2 * sp + r) * (NH * ND) +
                                     (ng0 + 8 * u) * 4);
    }
#pragma unroll
    for (int ks = 0; ks < 4; ++ks) {
      f16x8 af[2], bf[2];
#pragma unroll
      for (int mi = 0; mi < 2; ++mi) {
        const int row  = w * 64 + mi * 32 + l31;
        const int colb = (ks * 32 + g * 16) ^ ((row & 7) << 4);
        af[mi] = *(const f16x8*)((const char*)Wt + row * 128 + colb);
      }
#pragma unroll
      for (int di = 0; di < 2; ++di) {
        const int n = di * 32 + l31;
        bf[di] = *(const f16x8*)((const char*)XT + n * 144 + ks * 32 + g * 16);
      }
#pragma unroll
      for (int mi = 0; mi < 2; ++mi)
#pragma unroll
        for (int di = 0; di < 2; ++di)
          acc[mi][di] =
              __builtin_amdgcn_mfma_f32_32x32x16_f16(af[mi], bf[di], acc[mi][di], 0, 0, 0);
    }
  }

  const long bh = b * 16 + h;
  if (t == 0) {
    f16* K = Ksq + bh * (NM * ND);  // [u=d/8][m][d&7]
#pragma unroll
    for (int mi = 0; mi < 2; ++mi)
#pragma unroll
      for (int di = 0; di < 2; ++di)
#pragma unroll
        for (int r = 0; r < 16; ++r) {
          const int m = w * 64 + mi * 32 + (r & 3) + 8 * (r >> 2) + 4 * g;
          const int d = di * 32 + l31;
          K[((d >> 3) * 256 + m) * 8 + (d & 7)] = (f16)(acc[mi][di][r] + bias[m]);
        }
  } else {
    f16* V = Vsq + bh * (ND * NM);  // [u=m/8][d][m&7]
#pragma unroll
    for (int mi = 0; mi < 2; ++mi)
#pragma unroll
      for (int di = 0; di < 2; ++di)
#pragma unroll
        for (int q = 0; q < 4; ++q) {
          const int m0 = w * 64 + mi * 32 + 8 * q + 4 * g;  // m0&7 == 4g
          const int d  = di * 32 + l31;
          f16x2 p0 = __builtin_amdgcn_cvt_pkrtz(acc[mi][di][q * 4 + 0] + bias[m0 + 0],
                                                acc[mi][di][q * 4 + 1] + bias[m0 + 1]);
          f16x2 p1 = __builtin_amdgcn_cvt_pkrtz(acc[mi][di][q * 4 + 2] + bias[m0 + 2],
                                                acc[mi][di][q * 4 + 3] + bias[m0 + 3]);
          f16x4 pv; pv[0] = p0[0]; pv[1] = p0[1]; pv[2] = p1[0]; pv[3] = p1[1];
          *(f16x4*)(V + ((m0 >> 3) * 64 + d) * 8 + 4 * g) = pv;
        }
  }
}

// ---------------- kernel 2: attention (persistent K/V-in-LDS) ----------------
// 512 blocks (2 per (b,h)); block stages K,V once (64 KB LDS, k-run-major,
// conflict-free b128 reads), then loops 16 q-tiles of 128 rows (32 rows/wave).
// R3 numeric path exactly (max-subtract, p*inv before f16) + tree reductions
// (tree max == serial max bit-exactly) + Q double-buffer prefetch.
__global__ __launch_bounds__(256, 2) void k_attn(const float* __restrict__ Q,
                                                 const f16* __restrict__ Ksq,
                                                 const f16* __restrict__ Vsq,
                                                 float* __restrict__ Out) {
  const int xcd   = blockIdx.x & 7;
  const int local = blockIdx.x >> 3;        // 0..63
  const int bh    = xcd * 32 + (local >> 1);
  const int chunk = local & 1;
  const int b = bh >> 4, h = bh & 15;

  __shared__ __align__(16) f16 Klds[8 * 256 * 8];   // [u=d/8][m][8]  32 KB
  __shared__ __align__(16) f16 Vlds[32 * 64 * 8];   // [u=m/8][d][8]  32 KB

  const int tid = threadIdx.x, lane = tid & 63, w = tid >> 6;
  const int q = lane & 31, hi = lane >> 5;

  const float* Qlane = Q   + (((long)b * NL + q) * NH + h) * ND;
  float*       Olane = Out + (((long)b * NL + q) * NH + h) * ND;
  const float  c = 0.125f * 1.44269504088896f;

  // issue tile-0 Q loads first (complete while LDS stages)
  f32x4 qv[8];
  {
    const float* qp = Qlane + (long)(chunk * 2048 + w * 32) * (NH * ND) + hi * 8;
#pragma unroll
    for (int kt = 0; kt < 4; ++kt) {
      qv[2 * kt]     = *(const f32x4*)(qp + kt * 16);
      qv[2 * kt + 1] = *(const f32x4*)(qp + kt * 16 + 4);
    }
  }

  // stage K/V (identity copy, global_load_lds 16B)
  {
    const f16* Kg = Ksq + (long)bh * 16384;
    const f16* Vg = Vsq + (long)bh * 16384;
#pragma unroll
    for (int i = 0; i < 8; ++i)
      gload_lds16(Kg + w * 4096 + i * 512 + lane * 8, (char*)Klds + w * 8192 + i * 1024);
#pragma unroll
    for (int i = 0; i < 8; ++i)
      gload_lds16(Vg + w * 4096 + i * 512 + lane * 8, (char*)Vlds + w * 8192 + i * 1024);
  }
  __syncthreads();

  for (int it = 0; it < 16; ++it) {
    const int row0 = chunk * 2048 + it * 128 + w * 32;  // + q per lane

    // convert current Q tile to f16 B-frags
    union { f16x8 v; f16x2 h2[4]; } qb[4];
#pragma unroll
    for (int kt = 0; kt < 4; ++kt) {
      qb[kt].h2[0] = __builtin_amdgcn_cvt_pkrtz(qv[2 * kt][0], qv[2 * kt][1]);
      qb[kt].h2[1] = __builtin_amdgcn_cvt_pkrtz(qv[2 * kt][2], qv[2 * kt][3]);
      qb[kt].h2[2] = __builtin_amdgcn_cvt_pkrtz(qv[2 * kt + 1][0], qv[2 * kt + 1][1]);
      qb[kt].h2[3] = __builtin_amdgcn_cvt_pkrtz(qv[2 * kt + 1][2], qv[2 * kt + 1][3]);
    }

    // prefetch next tile's Q (latency hides under QK+softmax+PV)
    if (it + 1 < 16) {
      const float* qp = Qlane + (long)(row0 + 128) * (NH * ND) + hi * 8;
#pragma unroll
      for (int kt = 0; kt < 4; ++kt) {
        qv[2 * kt]     = *(const f32x4*)(qp + kt * 16);
        qv[2 * kt + 1] = *(const f32x4*)(qp + kt * 16 + 4);
      }
    }

    // QK^T: sa[mf] = S^T[m-frag][qcol]
    f32x16 sa[8];
#pragma unroll
    for (int mf = 0; mf < 8; ++mf)
#pragma unroll
      for (int r = 0; r < 16; ++r) sa[mf][r] = 0.f;

#pragma unroll
    for (int kt = 0; kt < 4; ++kt) {
#pragma unroll
      for (int mf = 0; mf < 8; ++mf) {
        f16x8 ka = *(const f16x8*)((const char*)Klds +
                                   ((2 * kt + hi) * 256 + mf * 32 + q) * 16);
        sa[mf] = __builtin_amdgcn_mfma_f32_32x32x16_f16(ka, qb[kt].v, sa[mf], 0, 0, 0);
      }
    }

    // tree max (== serial max exactly; max is order-independent)
    f32x16 mm = sa[0];
#pragma unroll
    for (int mf = 1; mf < 8; ++mf)
#pragma unroll
      for (int r = 0; r < 16; ++r) mm[r] = fmaxf(mm[r], sa[mf][r]);
    float m8_0 = fmaxf(mm[0], mm[8]),  m8_1 = fmaxf(mm[1], mm[9]);
    float m8_2 = fmaxf(mm[2], mm[10]), m8_3 = fmaxf(mm[3], mm[11]);
    float m8_4 = fmaxf(mm[4], mm[12]), m8_5 = fmaxf(mm[5], mm[13]);
    float m8_6 = fmaxf(mm[6], mm[14]), m8_7 = fmaxf(mm[7], mm[15]);
    float mx = fmaxf(fmaxf(fmaxf(m8_0, m8_1), fmaxf(m8_2, m8_3)),
                     fmaxf(fmaxf(m8_4, m8_5), fmaxf(m8_6, m8_7)));
    mx = fmaxf(mx, __shfl_xor(mx, 32));

    // p = exp2((s-mx)*c), tree-sum
#pragma unroll
    for (int mf = 0; mf < 8; ++mf)
#pragma unroll
      for (int r = 0; r < 16; ++r)
        sa[mf][r] = __builtin_amdgcn_exp2f((sa[mf][r] - mx) * c);

    f32x16 t0 = sa[0] + sa[1];
    f32x16 t1 = sa[2] + sa[3];
    f32x16 t2 = sa[4] + sa[5];
    f32x16 t3 = sa[6] + sa[7];
    t0 = (t0 + t1) + (t2 + t3);
    float s8_0 = t0[0] + t0[8],  s8_1 = t0[1] + t0[9];
    float s8_2 = t0[2] + t0[10], s8_3 = t0[3] + t0[11];
    float s8_4 = t0[4] + t0[12], s8_5 = t0[5] + t0[13];
    float s8_6 = t0[6] + t0[14], s8_7 = t0[7] + t0[15];
    float sum = ((s8_0 + s8_1) + (s8_2 + s8_3)) + ((s8_4 + s8_5) + (s8_6 + s8_7));
    sum += __shfl_xor(sum, 32);
    const float inv = 1.0f / sum;

    // PV: o[df] = ctx^T[d-frag][qcol]; normalized P via cvt_pk + permlane32_swap
    f32x16 o[2];
#pragma unroll
    for (int df = 0; df < 2; ++df)
#pragma unroll
      for (int r = 0; r < 16; ++r) o[df][r] = 0.f;

#pragma unroll
    for (int t = 0; t < 16; ++t) {
      const int fp = t >> 1, s = t & 1;
      int a0 = pk2(sa[fp][8 * s + 0] * inv, sa[fp][8 * s + 1] * inv);
      int a1 = pk2(sa[fp][8 * s + 2] * inv, sa[fp][8 * s + 3] * inv);
      int b0 = pk2(sa[fp][8 * s + 4] * inv, sa[fp][8 * s + 5] * inv);
      int b1 = pk2(sa[fp][8 * s + 6] * inv, sa[fp][8 * s + 7] * inv);
      asm volatile("v_permlane32_swap_b32 %0, %1" : "+v"(a0), "+v"(b0));
      asm volatile("v_permlane32_swap_b32 %0, %1" : "+v"(a1), "+v"(b1));
      union { int w4[4]; f16x8 v; } pb;
      pb.w4[0] = a0; pb.w4[1] = a1; pb.w4[2] = b0; pb.w4[3] = b1;
#pragma unroll
      for (int df = 0; df < 2; ++df) {
        f16x8 va = *(const f16x8*)((const char*)Vlds +
                                   ((2 * t + hi) * 64 + df * 32 + q) * 16);
        o[df] = __builtin_amdgcn_mfma_f32_32x32x16_f16(va, pb.v, o[df], 0, 0, 0);
      }
    }

    // store: lane q-col = row (row0+q); d = df*32 + rq*8 + hi*4 + (0..3)
    float* op = Olane + (long)row0 * (NH * ND);
#pragma unroll
    for (int df = 0; df < 2; ++df)
#pragma unroll
      for (int rq = 0; rq < 4; ++rq) {
        f32x4 st;
        st[0] = o[df][rq * 4 + 0]; st[1] = o[df][rq * 4 + 1];
        st[2] = o[df][rq * 4 + 2]; st[3] = o[df][rq * 4 + 3];
        *(f32x4*)(op + df * 32 + rq * 8 + hi * 4) = st;
      }
  }
}

extern "C" void kernel_launch(void* const* d_in, const int* in_sizes, int n_in,
                              void* d_out, int out_size, void* d_ws, size_t ws_size,
                              hipStream_t stream) {
  const float* Qp   = (const float*)d_in[0];
  const float* Kp   = (const float*)d_in[1];
  const float* Vp   = (const float*)d_in[2];
  const float* Wp   = (const float*)d_in[3];
  const float* bp   = (const float*)d_in[4];
  float*       Outp = (float*)d_out;

  char* ws = (char*)d_ws;
  f16* W16 = (f16*)ws;                              // 2 MB
  f16* Ksq = (f16*)(ws + (2l << 20));               // 8 MB
  f16* Vsq = (f16*)(ws + (2l << 20) + (8l << 20));  // 8 MB

  hipLaunchKernelGGL(k_wcvt, dim3(1024), dim3(256), 0, stream, Wp, W16);
  hipLaunchKernelGGL(k_squeeze, dim3(512), dim3(256), 0, stream, W16, Kp, Vp, bp, Ksq, Vsq);
  hipLaunchKernelGGL(k_attn, dim3(512), dim3(256), 0, stream, Qp, Ksq, Vsq, Outp);
}